// Round 6
// baseline (98.801 us; speedup 1.0000x reference)
//
#include <hip/hip_runtime.h>

// Problem constants (from reference)
#define NNODES 10000
#define DDEG   64
#define NEDGES 32768
#define FIN    64
#define HID    256

typedef __attribute__((ext_vector_type(8))) __bf16 bf16x8;
typedef __attribute__((ext_vector_type(4))) float  f32x4;
typedef __attribute__((ext_vector_type(8))) unsigned short u16x8;

__device__ __forceinline__ unsigned short f2bf(float f) {
    unsigned x = __float_as_uint(f);
    return (unsigned short)((x + 0x7FFFu + ((x >> 16) & 1u)) >> 16);  // RNE
}
__device__ __forceinline__ float b2f(unsigned short u) {
    return __uint_as_float(((unsigned)u) << 16);
}

// Transposed-weight workspace layout (bf16 elements): WT[n][k] = W[k][n]
#define OFF_XIJ1 0        // [256][64]
#define OFF_XIJ2 16384    // [256][256]
#define OFF_XCN1 81920    // [256][64]
#define OFF_XCN2 98304    // [256][256]
#define OFF_XCN3 163840   // [256][256]
#define OFF_LIN1 229376   // [256][256]
#define WT_TOTAL 294912

// Edge stage (1 edge per wave, latency hidden by TLP) + weight-prep piggyback.
__global__ __launch_bounds__(256) void edge_prep_k(const float* __restrict__ x,
                                                   const int* __restrict__ adj,
                                                   const int* __restrict__ tar,
                                                   const float* __restrict__ xij_w1,
                                                   const float* __restrict__ xij_w2,
                                                   const float* __restrict__ xcn_w1,
                                                   const float* __restrict__ xcn_w2,
                                                   const float* __restrict__ xcn_w3,
                                                   const float* __restrict__ lin_w1,
                                                   unsigned short* __restrict__ WT,
                                                   unsigned short* __restrict__ xij_g,
                                                   unsigned short* __restrict__ xcn_g) {
    const int wv   = threadIdx.x >> 6;
    const int lane = threadIdx.x & 63;
    const int e    = blockIdx.x * 4 + wv;      // grid = NEDGES/4 = 8192

    int i = tar[e];
    int j = tar[NEDGES + e];
    int ni = adj[i * DDEG + lane];
    int nj = adj[j * DDEG + lane];
    float xi = x[i * FIN + lane];
    float xj = x[j * FIN + lane];

    bool found = false;
#pragma unroll
    for (int b = 0; b < 64; ++b)
        found |= (ni == (int)__builtin_amdgcn_readlane(nj, b));
    unsigned long long m = __ballot(found);

    float acc = 0.f;
    while (m) {
        int a = __ffsll(m) - 1;
        m &= m - 1;
        int r = (int)__builtin_amdgcn_readlane(ni, a);
        acc += x[r * FIN + lane];
    }
    xij_g[(size_t)e * FIN + lane] = f2bf(xi * xj);
    xcn_g[(size_t)e * FIN + lane] = f2bf(acc);

    // ---- weight-prep piggyback: fp32 W[K,256] -> bf16 WT[256,K] ----
    if (blockIdx.x < WT_TOTAL / 256) {
        int idx = blockIdx.x * 256 + threadIdx.x;
        const float* src;
        int r, ks;
        if (idx < OFF_XIJ2)      { r = idx - OFF_XIJ1; ks = 6; src = xij_w1; }
        else if (idx < OFF_XCN1) { r = idx - OFF_XIJ2; ks = 8; src = xij_w2; }
        else if (idx < OFF_XCN2) { r = idx - OFF_XCN1; ks = 6; src = xcn_w1; }
        else if (idx < OFF_XCN3) { r = idx - OFF_XCN2; ks = 8; src = xcn_w2; }
        else if (idx < OFF_LIN1) { r = idx - OFF_XCN3; ks = 8; src = xcn_w3; }
        else                     { r = idx - OFF_LIN1; ks = 8; src = lin_w1; }
        int n = r >> ks;
        int k = r & ((1 << ks) - 1);
        WT[idx] = f2bf(src[k * HID + n]);
    }
}

// acc[2][4] (+)= A_lds[32 rows][K] @ WT[col-slice][K]^T (mfma 16x16x32 bf16),
// 2-deep prefetch of global B-fragments. A-frag lane l: row = m*16+(l&15),
// k = kk + 8*(l>>4)+i. LDS XOR swizzle: element ^= (row&7)<<3 (16B granular).
template <int K>
__device__ __forceinline__ void mfma_stage(const unsigned short* As,
                                           const unsigned short* __restrict__ Wt,
                                           int lr, int lg, int col0,
                                           f32x4 acc[2][4]) {
#pragma unroll
    for (int m = 0; m < 2; ++m)
#pragma unroll
        for (int n = 0; n < 4; ++n) acc[m][n] = (f32x4){0.f, 0.f, 0.f, 0.f};
    const int sw = (lr & 7) << 3;
    const unsigned short* pb[4];
#pragma unroll
    for (int n = 0; n < 4; ++n) pb[n] = Wt + (col0 + n * 16 + lr) * K + 8 * lg;

    bf16x8 bcur[4], bnxt[4];
#pragma unroll
    for (int n = 0; n < 4; ++n) bcur[n] = *reinterpret_cast<const bf16x8*>(pb[n]);

#pragma unroll
    for (int kk = 0; kk < K; kk += 32) {
        if (kk + 32 < K) {
#pragma unroll
            for (int n = 0; n < 4; ++n)
                bnxt[n] = *reinterpret_cast<const bf16x8*>(pb[n] + kk + 32);
        }
        bf16x8 a[2];
#pragma unroll
        for (int m = 0; m < 2; ++m)
            a[m] = *reinterpret_cast<const bf16x8*>(&As[(m * 16 + lr) * K + ((kk + 8 * lg) ^ sw)]);
#pragma unroll
        for (int m = 0; m < 2; ++m)
#pragma unroll
            for (int n = 0; n < 4; ++n)
                acc[m][n] = __builtin_amdgcn_mfma_f32_16x16x32_bf16(a[m], bcur[n], acc[m][n], 0, 0, 0);
        if (kk + 32 < K) {
#pragma unroll
            for (int n = 0; n < 4; ++n) bcur[n] = bnxt[n];
        }
    }
}

// MLP chain over 32-edge tiles, 4 waves/block (256 threads), grid 1024.
// Wave wv owns cols [wv*64, wv*64+64) over all 32 rows.
// D-frag lane l: row = m*16 + 4*(l>>4) + i, col = col0 + n*16 + (l&15).
__global__ __launch_bounds__(256) void mlp_k(const unsigned short* __restrict__ xij_g,
                                             const unsigned short* __restrict__ xcn_g,
                                             const unsigned short* __restrict__ WT,
                                             const float* __restrict__ xij_b1,
                                             const float* __restrict__ xij_b2,
                                             const float* __restrict__ xcn_b1,
                                             const float* __restrict__ xcn_b2,
                                             const float* __restrict__ xcn_b3,
                                             const float* __restrict__ lin_b1,
                                             const float* __restrict__ lin_w2,
                                             const float* __restrict__ lin_b2,
                                             const float* __restrict__ beta,
                                             float* __restrict__ out) {
    __shared__ unsigned short sXij[32 * 64];   // 4 KB, swizzled
    __shared__ unsigned short sXcn[32 * 64];   // 4 KB, swizzled
    __shared__ unsigned short sH[32 * 256];    // 16 KB, swizzled, reused
    __shared__ float sRed[4 * 32];             // 512 B

    const int tid  = threadIdx.x;
    const int wv   = tid >> 6;
    const int lane = tid & 63;
    const int lr   = lane & 15;
    const int lg   = lane >> 4;
    const int col0 = wv * 64;
    const int row0 = blockIdx.x * 32;

    // ---- stage tiles: one coalesced 16B/thread pass each, swizzled into LDS ----
    {
        int r  = tid >> 3;        // 0..31
        int k8 = tid & 7;         // 16B chunk within row
        int d  = r * 64 + ((k8 ^ (r & 7)) * 8);
        *reinterpret_cast<u16x8*>(&sXij[d]) =
            *reinterpret_cast<const u16x8*>(&xij_g[(size_t)(row0 + r) * 64 + k8 * 8]);
        *reinterpret_cast<u16x8*>(&sXcn[d]) =
            *reinterpret_cast<const u16x8*>(&xcn_g[(size_t)(row0 + r) * 64 + k8 * 8]);
    }
    __syncthreads();

    f32x4 acc[2][4];
    float bl[4];

    // ---- S1: h1 = relu(xij @ xij_w1 + b1) -> sH ----
    mfma_stage<64>(sXij, WT + OFF_XIJ1, lr, lg, col0, acc);
#pragma unroll
    for (int n = 0; n < 4; ++n) bl[n] = xij_b1[col0 + n * 16 + lr];
#pragma unroll
    for (int m = 0; m < 2; ++m)
#pragma unroll
        for (int n = 0; n < 4; ++n)
#pragma unroll
            for (int i = 0; i < 4; ++i) {
                int row = m * 16 + 4 * lg + i;
                int col = col0 + n * 16 + lr;
                sH[row * HID + (col ^ ((row & 7) << 3))] = f2bf(fmaxf(acc[m][n][i] + bl[n], 0.f));
            }
    __syncthreads();

    // ---- S2: h_ij = h1 @ xij_w2 + b2 -> registers (packed bf16, 16 VGPR) ----
    mfma_stage<256>(sH, WT + OFF_XIJ2, lr, lg, col0, acc);
#pragma unroll
    for (int n = 0; n < 4; ++n) bl[n] = xij_b2[col0 + n * 16 + lr];
    unsigned hij_lo[2][4], hij_hi[2][4];
#pragma unroll
    for (int m = 0; m < 2; ++m)
#pragma unroll
        for (int n = 0; n < 4; ++n) {
            hij_lo[m][n] = ((unsigned)f2bf(acc[m][n][1] + bl[n]) << 16) | f2bf(acc[m][n][0] + bl[n]);
            hij_hi[m][n] = ((unsigned)f2bf(acc[m][n][3] + bl[n]) << 16) | f2bf(acc[m][n][2] + bl[n]);
        }
    __syncthreads();   // S2 reads of sH done before S3 overwrites

    // ---- S3: t1 = relu(xcn @ xcn_w1 + b1) -> sH ----
    mfma_stage<64>(sXcn, WT + OFF_XCN1, lr, lg, col0, acc);
#pragma unroll
    for (int n = 0; n < 4; ++n) bl[n] = xcn_b1[col0 + n * 16 + lr];
#pragma unroll
    for (int m = 0; m < 2; ++m)
#pragma unroll
        for (int n = 0; n < 4; ++n)
#pragma unroll
            for (int i = 0; i < 4; ++i) {
                int row = m * 16 + 4 * lg + i;
                int col = col0 + n * 16 + lr;
                sH[row * HID + (col ^ ((row & 7) << 3))] = f2bf(fmaxf(acc[m][n][i] + bl[n], 0.f));
            }
    __syncthreads();

    // ---- S4: t2 = relu(t1 @ xcn_w2 + b2) -> sH in place ----
    mfma_stage<256>(sH, WT + OFF_XCN2, lr, lg, col0, acc);
    __syncthreads();   // all reads done before in-place overwrite
#pragma unroll
    for (int n = 0; n < 4; ++n) bl[n] = xcn_b2[col0 + n * 16 + lr];
#pragma unroll
    for (int m = 0; m < 2; ++m)
#pragma unroll
        for (int n = 0; n < 4; ++n)
#pragma unroll
            for (int i = 0; i < 4; ++i) {
                int row = m * 16 + 4 * lg + i;
                int col = col0 + n * 16 + lr;
                sH[row * HID + (col ^ ((row & 7) << 3))] = f2bf(fmaxf(acc[m][n][i] + bl[n], 0.f));
            }
    __syncthreads();

    // ---- S5: u = (t2 @ xcn_w3 + b3) * beta + h_ij -> sH in place ----
    mfma_stage<256>(sH, WT + OFF_XCN3, lr, lg, col0, acc);
    __syncthreads();
#pragma unroll
    for (int n = 0; n < 4; ++n) bl[n] = xcn_b3[col0 + n * 16 + lr];
    const float betaf = beta[0];
#pragma unroll
    for (int m = 0; m < 2; ++m)
#pragma unroll
        for (int n = 0; n < 4; ++n) {
            float h0 = b2f((unsigned short)(hij_lo[m][n] & 0xFFFF));
            float h1 = b2f((unsigned short)(hij_lo[m][n] >> 16));
            float h2 = b2f((unsigned short)(hij_hi[m][n] & 0xFFFF));
            float h3 = b2f((unsigned short)(hij_hi[m][n] >> 16));
            float v0 = (acc[m][n][0] + bl[n]) * betaf + h0;
            float v1 = (acc[m][n][1] + bl[n]) * betaf + h1;
            float v2 = (acc[m][n][2] + bl[n]) * betaf + h2;
            float v3 = (acc[m][n][3] + bl[n]) * betaf + h3;
            int rb = m * 16 + 4 * lg;
            int col = col0 + n * 16 + lr;
            sH[(rb + 0) * HID + (col ^ (((rb + 0) & 7) << 3))] = f2bf(v0);
            sH[(rb + 1) * HID + (col ^ (((rb + 1) & 7) << 3))] = f2bf(v1);
            sH[(rb + 2) * HID + (col ^ (((rb + 2) & 7) << 3))] = f2bf(v2);
            sH[(rb + 3) * HID + (col ^ (((rb + 3) & 7) << 3))] = f2bf(v3);
        }
    __syncthreads();

    // ---- S6: out = relu(u @ lin_w1 + lb1) . lin_w2 + lb2 ----
    mfma_stage<256>(sH, WT + OFF_LIN1, lr, lg, col0, acc);
#pragma unroll
    for (int n = 0; n < 4; ++n) bl[n] = lin_b1[col0 + n * 16 + lr];
    float w2l[4];
#pragma unroll
    for (int n = 0; n < 4; ++n) w2l[n] = lin_w2[col0 + n * 16 + lr];
#pragma unroll
    for (int m = 0; m < 2; ++m) {
        float p[4] = {0.f, 0.f, 0.f, 0.f};
#pragma unroll
        for (int n = 0; n < 4; ++n)
#pragma unroll
            for (int i = 0; i < 4; ++i)
                p[i] += fmaxf(acc[m][n][i] + bl[n], 0.f) * w2l[n];
#pragma unroll
        for (int i = 0; i < 4; ++i) {
            float s = p[i];
            s += __shfl_xor(s, 1);
            s += __shfl_xor(s, 2);
            s += __shfl_xor(s, 4);
            s += __shfl_xor(s, 8);
            if (lr == 0) sRed[wv * 32 + m * 16 + 4 * lg + i] = s;
        }
    }
    __syncthreads();
    if (tid < 32)
        out[row0 + tid] = sRed[tid] + sRed[32 + tid] + sRed[64 + tid] + sRed[96 + tid] + lin_b2[0];
}

extern "C" void kernel_launch(void* const* d_in, const int* in_sizes, int n_in,
                              void* d_out, int out_size, void* d_ws, size_t ws_size,
                              hipStream_t stream) {
    const float* x      = (const float*)d_in[0];
    const int*   adj    = (const int*)d_in[1];
    const int*   tar    = (const int*)d_in[2];
    const float* beta   = (const float*)d_in[3];
    const float* xcn_w1 = (const float*)d_in[4];
    const float* xcn_b1 = (const float*)d_in[5];
    const float* xcn_w2 = (const float*)d_in[6];
    const float* xcn_b2 = (const float*)d_in[7];
    const float* xcn_w3 = (const float*)d_in[8];
    const float* xcn_b3 = (const float*)d_in[9];
    const float* xij_w1 = (const float*)d_in[10];
    const float* xij_b1 = (const float*)d_in[11];
    const float* xij_w2 = (const float*)d_in[12];
    const float* xij_b2 = (const float*)d_in[13];
    const float* lin_w1 = (const float*)d_in[14];
    const float* lin_b1 = (const float*)d_in[15];
    const float* lin_w2 = (const float*)d_in[16];
    const float* lin_b2 = (const float*)d_in[17];

    unsigned short* WT    = (unsigned short*)d_ws;                 // 576 KiB
    unsigned short* xij_g = (unsigned short*)((char*)d_ws + 589824);   // 4 MiB
    unsigned short* xcn_g = (unsigned short*)((char*)d_ws + 4784128);  // 4 MiB

    edge_prep_k<<<NEDGES / 4, 256, 0, stream>>>(x, adj, tar,
                                                xij_w1, xij_w2, xcn_w1, xcn_w2, xcn_w3, lin_w1,
                                                WT, xij_g, xcn_g);
    mlp_k<<<NEDGES / 32, 256, 0, stream>>>(xij_g, xcn_g, WT,
                                           xij_b1, xij_b2, xcn_b1, xcn_b2, xcn_b3,
                                           lin_b1, lin_w2, lin_b2, beta, (float*)d_out);
}

// Round 7
// 83.393 us; speedup vs baseline: 1.1848x; 1.1848x over previous
//
#include <hip/hip_runtime.h>

// Problem constants (from reference)
#define NNODES 10000
#define DDEG   64
#define NEDGES 32768
#define FIN    64
#define HID    256

typedef __attribute__((ext_vector_type(8))) __bf16 bf16x8;
typedef __attribute__((ext_vector_type(4))) float  f32x4;
typedef __attribute__((ext_vector_type(8))) unsigned short u16x8;

__device__ __forceinline__ unsigned short f2bf(float f) {
    unsigned x = __float_as_uint(f);
    return (unsigned short)((x + 0x7FFFu + ((x >> 16) & 1u)) >> 16);  // RNE
}
__device__ __forceinline__ float b2f(unsigned short u) {
    return __uint_as_float(((unsigned)u) << 16);
}

// Blocked transposed-weight layout (bf16): WT[k>>5][n][k&31], block stride 8192 elems.
// B-frag load for (col, kk): 16 consecutive cols x 64B = 1KB contiguous per wave. Coalesced.
#define OFF_XIJ1 0        // K=64  : 2 blocks
#define OFF_XIJ2 16384    // K=256 : 8 blocks
#define OFF_XCN1 81920    // K=64
#define OFF_XCN2 98304    // K=256
#define OFF_XCN3 163840   // K=256
#define OFF_LIN1 229376   // K=256
#define WT_TOTAL 294912

// Edge stage (1 edge per wave, latency hidden by TLP) + weight-prep piggyback.
__global__ __launch_bounds__(256) void edge_prep_k(const float* __restrict__ x,
                                                   const int* __restrict__ adj,
                                                   const int* __restrict__ tar,
                                                   const float* __restrict__ xij_w1,
                                                   const float* __restrict__ xij_w2,
                                                   const float* __restrict__ xcn_w1,
                                                   const float* __restrict__ xcn_w2,
                                                   const float* __restrict__ xcn_w3,
                                                   const float* __restrict__ lin_w1,
                                                   unsigned short* __restrict__ WT,
                                                   unsigned short* __restrict__ xij_g,
                                                   unsigned short* __restrict__ xcn_g) {
    const int wv   = threadIdx.x >> 6;
    const int lane = threadIdx.x & 63;
    const int e    = blockIdx.x * 4 + wv;      // grid = NEDGES/4 = 8192

    int i = tar[e];
    int j = tar[NEDGES + e];
    int ni = adj[i * DDEG + lane];
    int nj = adj[j * DDEG + lane];
    float xi = x[i * FIN + lane];
    float xj = x[j * FIN + lane];

    bool found = false;
#pragma unroll
    for (int b = 0; b < 64; ++b)
        found |= (ni == (int)__builtin_amdgcn_readlane(nj, b));
    unsigned long long m = __ballot(found);

    float acc = 0.f;
    while (m) {
        int a = __ffsll(m) - 1;
        m &= m - 1;
        int r = (int)__builtin_amdgcn_readlane(ni, a);
        acc += x[r * FIN + lane];
    }
    xij_g[(size_t)e * FIN + lane] = f2bf(xi * xj);
    xcn_g[(size_t)e * FIN + lane] = f2bf(acc);

    // ---- weight-prep piggyback: fp32 W[K,256] -> blocked bf16 WT ----
    if (blockIdx.x < WT_TOTAL / 256) {
        int idx = blockIdx.x * 256 + threadIdx.x;
        const float* src;
        int r;
        if (idx < OFF_XIJ2)      { r = idx - OFF_XIJ1; src = xij_w1; }
        else if (idx < OFF_XCN1) { r = idx - OFF_XIJ2; src = xij_w2; }
        else if (idx < OFF_XCN2) { r = idx - OFF_XCN1; src = xcn_w1; }
        else if (idx < OFF_XCN3) { r = idx - OFF_XCN2; src = xcn_w2; }
        else if (idx < OFF_LIN1) { r = idx - OFF_XCN3; src = xcn_w3; }
        else                     { r = idx - OFF_LIN1; src = lin_w1; }
        int kb  = r >> 13;            // 32-k block
        int n   = (r & 8191) >> 5;    // col
        int klo = r & 31;
        WT[idx] = f2bf(src[(kb * 32 + klo) * HID + n]);
    }
}

// Dual-stream k-loop: two independent MFMA streams (2x ILP), each NK 32-wide k-steps.
// accX[2][4] += AsX[32 rows] @ WtX-panel. B from blocked-WT (1KB coalesced loads).
// A-frag lane l: row = m*16+(l&15), k = koff + s*32 + 8*(l>>4)+i, LDS XOR swizzle
// element ^= ((row&7)<<3). B-frag: Wt[(kb+s)<<13 | (col0+n*16+lr)*32 | 8*lg].
template <int NK>
__device__ __forceinline__ void dual_mfma(const unsigned short* AsA, int ldaA, int koffA,
                                          const unsigned short* __restrict__ WtA, int kbA,
                                          const unsigned short* AsB, int ldaB, int koffB,
                                          const unsigned short* __restrict__ WtB, int kbB,
                                          int lr, int lg, int col0,
                                          f32x4 accA[2][4], f32x4 accB[2][4]) {
    const int sw = (lr & 7) << 3;
#pragma unroll
    for (int s = 0; s < NK; ++s) {
        bf16x8 bA[4], bB[4], aA[2], aB[2];
#pragma unroll
        for (int n = 0; n < 4; ++n)
            bA[n] = *reinterpret_cast<const bf16x8*>(
                &WtA[((kbA + s) << 13) + (col0 + n * 16 + lr) * 32 + 8 * lg]);
#pragma unroll
        for (int n = 0; n < 4; ++n)
            bB[n] = *reinterpret_cast<const bf16x8*>(
                &WtB[((kbB + s) << 13) + (col0 + n * 16 + lr) * 32 + 8 * lg]);
#pragma unroll
        for (int m = 0; m < 2; ++m)
            aA[m] = *reinterpret_cast<const bf16x8*>(
                &AsA[(m * 16 + lr) * ldaA + ((koffA + s * 32 + 8 * lg) ^ sw)]);
#pragma unroll
        for (int m = 0; m < 2; ++m)
            aB[m] = *reinterpret_cast<const bf16x8*>(
                &AsB[(m * 16 + lr) * ldaB + ((koffB + s * 32 + 8 * lg) ^ sw)]);
#pragma unroll
        for (int m = 0; m < 2; ++m)
#pragma unroll
            for (int n = 0; n < 4; ++n)
                accA[m][n] = __builtin_amdgcn_mfma_f32_16x16x32_bf16(aA[m], bA[n], accA[m][n], 0, 0, 0);
#pragma unroll
        for (int m = 0; m < 2; ++m)
#pragma unroll
            for (int n = 0; n < 4; ++n)
                accB[m][n] = __builtin_amdgcn_mfma_f32_16x16x32_bf16(aB[m], bB[n], accB[m][n], 0, 0, 0);
    }
}

__device__ __forceinline__ void zero_acc(f32x4 acc[2][4]) {
#pragma unroll
    for (int m = 0; m < 2; ++m)
#pragma unroll
        for (int n = 0; n < 4; ++n) acc[m][n] = (f32x4){0.f, 0.f, 0.f, 0.f};
}

// MLP over 32-edge tiles, 4 waves/block, 4 dual-stream phases.
// Wave wv owns cols [wv*64, wv*64+64). D-frag lane l: row=m*16+4*(l>>4)+i, col=col0+n*16+(l&15).
__global__ __launch_bounds__(256) void mlp_k(const unsigned short* __restrict__ xij_g,
                                             const unsigned short* __restrict__ xcn_g,
                                             const unsigned short* __restrict__ WT,
                                             const float* __restrict__ xij_b1,
                                             const float* __restrict__ xij_b2,
                                             const float* __restrict__ xcn_b1,
                                             const float* __restrict__ xcn_b2,
                                             const float* __restrict__ xcn_b3,
                                             const float* __restrict__ lin_b1,
                                             const float* __restrict__ lin_w2,
                                             const float* __restrict__ lin_b2,
                                             const float* __restrict__ beta,
                                             float* __restrict__ out) {
    __shared__ unsigned short sXij[32 * 64];   // 4 KB, swizzled
    __shared__ unsigned short sXcn[32 * 64];   // 4 KB, swizzled
    __shared__ unsigned short sHa[32 * 256];   // 16 KB (xij branch h1, later u)
    __shared__ unsigned short sHb[32 * 256];   // 16 KB (xcn branch t1 -> t2)
    __shared__ float sRed[4 * 32];             // 512 B

    const int tid  = threadIdx.x;
    const int wv   = tid >> 6;
    const int lane = tid & 63;
    const int lr   = lane & 15;
    const int lg   = lane >> 4;
    const int col0 = wv * 64;
    const int row0 = blockIdx.x * 32;

    // ---- stage tiles: coalesced 16B/thread, swizzled into LDS ----
    {
        int r  = tid >> 3;        // 0..31
        int k8 = tid & 7;
        int d  = r * 64 + ((k8 ^ (r & 7)) * 8);
        *reinterpret_cast<u16x8*>(&sXij[d]) =
            *reinterpret_cast<const u16x8*>(&xij_g[(size_t)(row0 + r) * 64 + k8 * 8]);
        *reinterpret_cast<u16x8*>(&sXcn[d]) =
            *reinterpret_cast<const u16x8*>(&xcn_g[(size_t)(row0 + r) * 64 + k8 * 8]);
    }
    const float betaf = beta[0];
    __syncthreads();

    f32x4 accA[2][4], accB[2][4];
    float blA[4], blB[4];

    // ---- P1: h1 = relu(xij@xij_w1+b1) || t1 = relu(xcn@xcn_w1+b1) ----
    zero_acc(accA); zero_acc(accB);
#pragma unroll
    for (int n = 0; n < 4; ++n) { blA[n] = xij_b1[col0 + n * 16 + lr]; blB[n] = xcn_b1[col0 + n * 16 + lr]; }
    dual_mfma<2>(sXij, 64, 0, WT + OFF_XIJ1, 0,
                 sXcn, 64, 0, WT + OFF_XCN1, 0, lr, lg, col0, accA, accB);
#pragma unroll
    for (int m = 0; m < 2; ++m)
#pragma unroll
        for (int n = 0; n < 4; ++n)
#pragma unroll
            for (int i = 0; i < 4; ++i) {
                int row = m * 16 + 4 * lg + i;
                int col = col0 + n * 16 + lr;
                int sx  = row * HID + (col ^ ((row & 7) << 3));
                sHa[sx] = f2bf(fmaxf(accA[m][n][i] + blA[n], 0.f));
                sHb[sx] = f2bf(fmaxf(accB[m][n][i] + blB[n], 0.f));
            }
    __syncthreads();

    // ---- P2: h_ij = h1@xij_w2+b2 (->regs) || t2 = relu(t1@xcn_w2+b2) (->sHb) ----
    zero_acc(accA); zero_acc(accB);
#pragma unroll
    for (int n = 0; n < 4; ++n) { blA[n] = xij_b2[col0 + n * 16 + lr]; blB[n] = xcn_b2[col0 + n * 16 + lr]; }
    dual_mfma<8>(sHa, 256, 0, WT + OFF_XIJ2, 0,
                 sHb, 256, 0, WT + OFF_XCN2, 0, lr, lg, col0, accA, accB);
    unsigned hij_lo[2][4], hij_hi[2][4];
#pragma unroll
    for (int m = 0; m < 2; ++m)
#pragma unroll
        for (int n = 0; n < 4; ++n) {
            hij_lo[m][n] = ((unsigned)f2bf(accA[m][n][1] + blA[n]) << 16) | f2bf(accA[m][n][0] + blA[n]);
            hij_hi[m][n] = ((unsigned)f2bf(accA[m][n][3] + blA[n]) << 16) | f2bf(accA[m][n][2] + blA[n]);
        }
    __syncthreads();   // all k-loop reads of sHa/sHb done
#pragma unroll
    for (int m = 0; m < 2; ++m)
#pragma unroll
        for (int n = 0; n < 4; ++n)
#pragma unroll
            for (int i = 0; i < 4; ++i) {
                int row = m * 16 + 4 * lg + i;
                int col = col0 + n * 16 + lr;
                sHb[row * HID + (col ^ ((row & 7) << 3))] = f2bf(fmaxf(accB[m][n][i] + blB[n], 0.f));
            }
    __syncthreads();

    // ---- P3 (split-K dual): u = (t2@xcn_w3+b3)*beta + h_ij -> sHa ----
    zero_acc(accA); zero_acc(accB);
#pragma unroll
    for (int n = 0; n < 4; ++n) blA[n] = xcn_b3[col0 + n * 16 + lr];
    dual_mfma<4>(sHb, 256, 0,   WT + OFF_XCN3, 0,
                 sHb, 256, 128, WT + OFF_XCN3, 4, lr, lg, col0, accA, accB);
    __syncthreads();   // reads of sHb done; sHa writes next (P2 readers already past barrier)
#pragma unroll
    for (int m = 0; m < 2; ++m)
#pragma unroll
        for (int n = 0; n < 4; ++n) {
            float h0 = b2f((unsigned short)(hij_lo[m][n] & 0xFFFF));
            float h1 = b2f((unsigned short)(hij_lo[m][n] >> 16));
            float h2 = b2f((unsigned short)(hij_hi[m][n] & 0xFFFF));
            float h3 = b2f((unsigned short)(hij_hi[m][n] >> 16));
            float v0 = (accA[m][n][0] + accB[m][n][0] + blA[n]) * betaf + h0;
            float v1 = (accA[m][n][1] + accB[m][n][1] + blA[n]) * betaf + h1;
            float v2 = (accA[m][n][2] + accB[m][n][2] + blA[n]) * betaf + h2;
            float v3 = (accA[m][n][3] + accB[m][n][3] + blA[n]) * betaf + h3;
            int rb = m * 16 + 4 * lg;
            int col = col0 + n * 16 + lr;
            sHa[(rb + 0) * HID + (col ^ (((rb + 0) & 7) << 3))] = f2bf(v0);
            sHa[(rb + 1) * HID + (col ^ (((rb + 1) & 7) << 3))] = f2bf(v1);
            sHa[(rb + 2) * HID + (col ^ (((rb + 2) & 7) << 3))] = f2bf(v2);
            sHa[(rb + 3) * HID + (col ^ (((rb + 3) & 7) << 3))] = f2bf(v3);
        }
    __syncthreads();

    // ---- P4 (split-K dual): out = relu(u@lin_w1+lb1).lin_w2 + lb2 ----
    zero_acc(accA); zero_acc(accB);
#pragma unroll
    for (int n = 0; n < 4; ++n) blA[n] = lin_b1[col0 + n * 16 + lr];
    float w2l[4];
#pragma unroll
    for (int n = 0; n < 4; ++n) w2l[n] = lin_w2[col0 + n * 16 + lr];
    dual_mfma<4>(sHa, 256, 0,   WT + OFF_LIN1, 0,
                 sHa, 256, 128, WT + OFF_LIN1, 4, lr, lg, col0, accA, accB);
#pragma unroll
    for (int m = 0; m < 2; ++m) {
        float p[4] = {0.f, 0.f, 0.f, 0.f};
#pragma unroll
        for (int n = 0; n < 4; ++n)
#pragma unroll
            for (int i = 0; i < 4; ++i)
                p[i] += fmaxf(accA[m][n][i] + accB[m][n][i] + blA[n], 0.f) * w2l[n];
#pragma unroll
        for (int i = 0; i < 4; ++i) {
            float s = p[i];
            s += __shfl_xor(s, 1);
            s += __shfl_xor(s, 2);
            s += __shfl_xor(s, 4);
            s += __shfl_xor(s, 8);
            if (lr == 0) sRed[wv * 32 + m * 16 + 4 * lg + i] = s;
        }
    }
    __syncthreads();
    if (tid < 32)
        out[row0 + tid] = sRed[tid] + sRed[32 + tid] + sRed[64 + tid] + sRed[96 + tid] + lin_b2[0];
}

extern "C" void kernel_launch(void* const* d_in, const int* in_sizes, int n_in,
                              void* d_out, int out_size, void* d_ws, size_t ws_size,
                              hipStream_t stream) {
    const float* x      = (const float*)d_in[0];
    const int*   adj    = (const int*)d_in[1];
    const int*   tar    = (const int*)d_in[2];
    const float* beta   = (const float*)d_in[3];
    const float* xcn_w1 = (const float*)d_in[4];
    const float* xcn_b1 = (const float*)d_in[5];
    const float* xcn_w2 = (const float*)d_in[6];
    const float* xcn_b2 = (const float*)d_in[7];
    const float* xcn_w3 = (const float*)d_in[8];
    const float* xcn_b3 = (const float*)d_in[9];
    const float* xij_w1 = (const float*)d_in[10];
    const float* xij_b1 = (const float*)d_in[11];
    const float* xij_w2 = (const float*)d_in[12];
    const float* xij_b2 = (const float*)d_in[13];
    const float* lin_w1 = (const float*)d_in[14];
    const float* lin_b1 = (const float*)d_in[15];
    const float* lin_w2 = (const float*)d_in[16];
    const float* lin_b2 = (const float*)d_in[17];

    unsigned short* WT    = (unsigned short*)d_ws;                     // 576 KiB
    unsigned short* xij_g = (unsigned short*)((char*)d_ws + 589824);   // 4 MiB
    unsigned short* xcn_g = (unsigned short*)((char*)d_ws + 4784128);  // 4 MiB

    edge_prep_k<<<NEDGES / 4, 256, 0, stream>>>(x, adj, tar,
                                                xij_w1, xij_w2, xcn_w1, xcn_w2, xcn_w3, lin_w1,
                                                WT, xij_g, xcn_g);
    mlp_k<<<NEDGES / 32, 256, 0, stream>>>(xij_g, xcn_g, WT,
                                           xij_b1, xij_b2, xcn_b1, xcn_b2, xcn_b3,
                                           lin_b1, lin_w2, lin_b2, beta, (float*)d_out);
}

// Round 8
// 76.472 us; speedup vs baseline: 1.2920x; 1.0905x over previous
//
#include <hip/hip_runtime.h>

// Problem constants (from reference)
#define NNODES 10000
#define DDEG   64
#define NEDGES 32768
#define FIN    64
#define HID    256

typedef __attribute__((ext_vector_type(8))) __bf16 bf16x8;
typedef __attribute__((ext_vector_type(4))) float  f32x4;

__device__ __forceinline__ unsigned short f2bf(float f) {
    unsigned x = __float_as_uint(f);
    return (unsigned short)((x + 0x7FFFu + ((x >> 16) & 1u)) >> 16);  // RNE
}
__device__ __forceinline__ float b2f(unsigned short u) {
    return __uint_as_float(((unsigned)u) << 16);
}

// Blocked transposed-weight layout (bf16): WT[k>>5][n][k&31], block stride 8192 elems.
#define OFF_XIJ1 0        // K=64  : 2 blocks
#define OFF_XIJ2 16384    // K=256 : 8 blocks
#define OFF_XCN1 81920
#define OFF_XCN2 98304
#define OFF_XCN3 163840
#define OFF_LIN1 229376
#define WT_TOTAL 294912

// ---- async global->LDS staging (wave-uniform LDS base + lane*16B) ----
__device__ __forceinline__ void gll16(const unsigned short* g, unsigned short* l) {
    __builtin_amdgcn_global_load_lds(
        (const __attribute__((address_space(1))) unsigned int*)g,
        (__attribute__((address_space(3))) unsigned int*)l, 16, 0, 0);
}
// 16KB tile: 4 issues x (256 thr x 16B)
__device__ __forceinline__ void stage16k(const unsigned short* g, unsigned short* l, int tid) {
    int wv = tid >> 6;
#pragma unroll
    for (int c = 0; c < 4; ++c)
        gll16(g + c * 2048 + tid * 8, l + c * 2048 + wv * 512);
}
// 8KB tile: 2 issues
__device__ __forceinline__ void stage8k(const unsigned short* g, unsigned short* l, int tid) {
    int wv = tid >> 6;
#pragma unroll
    for (int c = 0; c < 2; ++c)
        gll16(g + c * 2048 + tid * 8, l + c * 2048 + wv * 512);
}

// Edge stage (1 edge per wave, TLP-hidden) + weight-prep piggyback.
// xij/xcn written PRE-SWIZZLED (elem ^= (row&7)<<3) so mlp's linear global_load_lds
// staging lands in the swizzled layout the A-fragment ds_reads expect.
__global__ __launch_bounds__(256) void edge_prep_k(const float* __restrict__ x,
                                                   const int* __restrict__ adj,
                                                   const int* __restrict__ tar,
                                                   const float* __restrict__ xij_w1,
                                                   const float* __restrict__ xij_w2,
                                                   const float* __restrict__ xcn_w1,
                                                   const float* __restrict__ xcn_w2,
                                                   const float* __restrict__ xcn_w3,
                                                   const float* __restrict__ lin_w1,
                                                   unsigned short* __restrict__ WT,
                                                   unsigned short* __restrict__ xij_g,
                                                   unsigned short* __restrict__ xcn_g) {
    const int wv   = threadIdx.x >> 6;
    const int lane = threadIdx.x & 63;
    const int e    = blockIdx.x * 4 + wv;      // grid = NEDGES/4 = 8192

    int i = tar[e];
    int j = tar[NEDGES + e];
    int ni = adj[i * DDEG + lane];
    int nj = adj[j * DDEG + lane];
    float xi = x[i * FIN + lane];
    float xj = x[j * FIN + lane];

    bool found = false;
#pragma unroll
    for (int b = 0; b < 64; ++b)
        found |= (ni == (int)__builtin_amdgcn_readlane(nj, b));
    unsigned long long m = __ballot(found);

    float acc = 0.f;
    while (m) {
        int a = __ffsll(m) - 1;
        m &= m - 1;
        int r = (int)__builtin_amdgcn_readlane(ni, a);
        acc += x[r * FIN + lane];
    }
    int sl = lane ^ ((e & 7) << 3);            // pre-swizzle (row&7 == e&7)
    xij_g[(size_t)e * FIN + sl] = f2bf(xi * xj);
    xcn_g[(size_t)e * FIN + sl] = f2bf(acc);

    // ---- weight-prep piggyback: fp32 W[K,256] -> blocked bf16 WT ----
    if (blockIdx.x < WT_TOTAL / 256) {
        int idx = blockIdx.x * 256 + threadIdx.x;
        const float* src;
        int r;
        if (idx < OFF_XIJ2)      { r = idx - OFF_XIJ1; src = xij_w1; }
        else if (idx < OFF_XCN1) { r = idx - OFF_XIJ2; src = xij_w2; }
        else if (idx < OFF_XCN2) { r = idx - OFF_XCN1; src = xcn_w1; }
        else if (idx < OFF_XCN3) { r = idx - OFF_XCN2; src = xcn_w2; }
        else if (idx < OFF_LIN1) { r = idx - OFF_XCN3; src = xcn_w3; }
        else                     { r = idx - OFF_LIN1; src = lin_w1; }
        int kb  = r >> 13;
        int n   = (r & 8191) >> 5;
        int klo = r & 31;
        WT[idx] = f2bf(src[(kb * 32 + klo) * HID + n]);
    }
}

// One GEMM phase: acc[4][4] = A_lds[64xK] @ W (K = NSTEP*32), B double-buffered in
// sB[2][8192] via global_load_lds one tile ahead; tile0 of the NEXT phase staged in
// the final step. Phase starts and ends with buf=0 (NSTEP even).
// A-frag lane l: row=m*16+(l&15), k=s*32+8*(l>>4)+i, elem ^= (row&7)<<3 (swizzle).
// B-frag: cur[(col0+n*16+lr)*32 + 8*lg] (conflict-free bijective 1KB wave read).
template <int NSTEP, int LDA>
__device__ __forceinline__ void gemm_phase(const unsigned short* As,
                                           unsigned short* sB,
                                           const unsigned short* __restrict__ Wt,
                                           const unsigned short* nextW,
                                           int lr, int lg, int col0, int tid,
                                           f32x4 acc[4][4]) {
#pragma unroll
    for (int m = 0; m < 4; ++m)
#pragma unroll
        for (int n = 0; n < 4; ++n) acc[m][n] = (f32x4){0.f, 0.f, 0.f, 0.f};
    const int sw = (lr & 7) << 3;
#pragma unroll
    for (int s = 0; s < NSTEP; ++s) {
        unsigned short* cur = sB + (s & 1) * 8192;
        unsigned short* nxt = sB + ((s & 1) ^ 1) * 8192;
        if (s + 1 < NSTEP)      stage16k(Wt + (s + 1) * 8192, nxt, tid);
        else if (nextW)         stage16k(nextW, nxt, tid);
        bf16x8 a[4], b[4];
#pragma unroll
        for (int n = 0; n < 4; ++n)
            b[n] = *reinterpret_cast<const bf16x8*>(&cur[(col0 + n * 16 + lr) * 32 + 8 * lg]);
#pragma unroll
        for (int m = 0; m < 4; ++m)
            a[m] = *reinterpret_cast<const bf16x8*>(&As[(m * 16 + lr) * LDA + ((s * 32 + 8 * lg) ^ sw)]);
#pragma unroll
        for (int m = 0; m < 4; ++m)
#pragma unroll
            for (int n = 0; n < 4; ++n)
                acc[m][n] = __builtin_amdgcn_mfma_f32_16x16x32_bf16(a[m], b[n], acc[m][n], 0, 0, 0);
        __syncthreads();   // drains vmcnt (staged tile ready) + lgkmcnt
    }
}

// Fused MLP over 64-edge tiles; 4 waves (256 thr); wave wv: cols [wv*64,+64), rows 0..63.
// D-frag lane l: row=m*16+4*(l>>4)+i, col=col0+n*16+(l&15).
// LDS 73KB -> 2 blocks/CU; grid 512 = exactly 2 blocks/CU (cross-block latency hiding).
__global__ __launch_bounds__(256) void mlp_k(const unsigned short* __restrict__ xij_g,
                                             const unsigned short* __restrict__ xcn_g,
                                             const unsigned short* __restrict__ WT,
                                             const float* __restrict__ xij_b1,
                                             const float* __restrict__ xij_b2,
                                             const float* __restrict__ xcn_b1,
                                             const float* __restrict__ xcn_b2,
                                             const float* __restrict__ xcn_b3,
                                             const float* __restrict__ lin_b1,
                                             const float* __restrict__ lin_w2,
                                             const float* __restrict__ lin_b2,
                                             const float* __restrict__ beta,
                                             float* __restrict__ out) {
    __shared__ unsigned short sX[64 * 64];     // 8 KB: xij, then xcn (restaged)
    __shared__ unsigned short sH[64 * 256];    // 32 KB activation buffer (in-place reuse)
    __shared__ unsigned short sB[2 * 8192];    // 32 KB weight double-buffer
    __shared__ float sRed[4 * 64];             // 1 KB

    const int tid  = threadIdx.x;
    const int wv   = tid >> 6;
    const int lane = tid & 63;
    const int lr   = lane & 15;
    const int lg   = lane >> 4;
    const int col0 = wv * 64;
    const int row0 = blockIdx.x * 64;

    // prologue: stage xij tile + first weight tile
    stage8k(xij_g + (size_t)row0 * FIN, sX, tid);
    stage16k(WT + OFF_XIJ1, sB, tid);
    const float betaf = beta[0];
    __syncthreads();

    f32x4 acc[4][4];
    float bl[4];

    // ---- P1a: h1 = relu(xij @ xij_w1 + b1) -> sH ----
    gemm_phase<2, 64>(sX, sB, WT + OFF_XIJ1, WT + OFF_XIJ2, lr, lg, col0, tid, acc);
#pragma unroll
    for (int n = 0; n < 4; ++n) bl[n] = xij_b1[col0 + n * 16 + lr];
#pragma unroll
    for (int m = 0; m < 4; ++m)
#pragma unroll
        for (int n = 0; n < 4; ++n)
#pragma unroll
            for (int i = 0; i < 4; ++i) {
                int row = m * 16 + 4 * lg + i;
                int col = col0 + n * 16 + lr;
                sH[row * HID + (col ^ ((row & 7) << 3))] = f2bf(fmaxf(acc[m][n][i] + bl[n], 0.f));
            }
    stage8k(xcn_g + (size_t)row0 * FIN, sX, tid);   // sX dead after P1a; restage for P1b
    __syncthreads();

    // ---- P2a: h_ij = h1 @ xij_w2 + b2 -> registers (packed bf16) ----
    gemm_phase<8, 256>(sH, sB, WT + OFF_XIJ2, WT + OFF_XCN1, lr, lg, col0, tid, acc);
#pragma unroll
    for (int n = 0; n < 4; ++n) bl[n] = xij_b2[col0 + n * 16 + lr];
    unsigned hij_lo[4][4], hij_hi[4][4];
#pragma unroll
    for (int m = 0; m < 4; ++m)
#pragma unroll
        for (int n = 0; n < 4; ++n) {
            hij_lo[m][n] = ((unsigned)f2bf(acc[m][n][1] + bl[n]) << 16) | f2bf(acc[m][n][0] + bl[n]);
            hij_hi[m][n] = ((unsigned)f2bf(acc[m][n][3] + bl[n]) << 16) | f2bf(acc[m][n][2] + bl[n]);
        }
    // (no barrier needed: hij is wave-private; buffers already fenced by k-loop syncs)

    // ---- P1b: t1 = relu(xcn @ xcn_w1 + b1) -> sH ----
    gemm_phase<2, 64>(sX, sB, WT + OFF_XCN1, WT + OFF_XCN2, lr, lg, col0, tid, acc);
#pragma unroll
    for (int n = 0; n < 4; ++n) bl[n] = xcn_b1[col0 + n * 16 + lr];
#pragma unroll
    for (int m = 0; m < 4; ++m)
#pragma unroll
        for (int n = 0; n < 4; ++n)
#pragma unroll
            for (int i = 0; i < 4; ++i) {
                int row = m * 16 + 4 * lg + i;
                int col = col0 + n * 16 + lr;
                sH[row * HID + (col ^ ((row & 7) << 3))] = f2bf(fmaxf(acc[m][n][i] + bl[n], 0.f));
            }
    __syncthreads();

    // ---- P2b: t2 = relu(t1 @ xcn_w2 + b2) -> sH (in place; k-loop reads all done) ----
    gemm_phase<8, 256>(sH, sB, WT + OFF_XCN2, WT + OFF_XCN3, lr, lg, col0, tid, acc);
#pragma unroll
    for (int n = 0; n < 4; ++n) bl[n] = xcn_b2[col0 + n * 16 + lr];
#pragma unroll
    for (int m = 0; m < 4; ++m)
#pragma unroll
        for (int n = 0; n < 4; ++n)
#pragma unroll
            for (int i = 0; i < 4; ++i) {
                int row = m * 16 + 4 * lg + i;
                int col = col0 + n * 16 + lr;
                sH[row * HID + (col ^ ((row & 7) << 3))] = f2bf(fmaxf(acc[m][n][i] + bl[n], 0.f));
            }
    __syncthreads();

    // ---- P3: u = (t2 @ xcn_w3 + b3) * beta + h_ij -> sH (in place) ----
    gemm_phase<8, 256>(sH, sB, WT + OFF_XCN3, WT + OFF_LIN1, lr, lg, col0, tid, acc);
#pragma unroll
    for (int n = 0; n < 4; ++n) bl[n] = xcn_b3[col0 + n * 16 + lr];
#pragma unroll
    for (int m = 0; m < 4; ++m)
#pragma unroll
        for (int n = 0; n < 4; ++n) {
            float h0 = b2f((unsigned short)(hij_lo[m][n] & 0xFFFF));
            float h1 = b2f((unsigned short)(hij_lo[m][n] >> 16));
            float h2 = b2f((unsigned short)(hij_hi[m][n] & 0xFFFF));
            float h3 = b2f((unsigned short)(hij_hi[m][n] >> 16));
            float v0 = (acc[m][n][0] + bl[n]) * betaf + h0;
            float v1 = (acc[m][n][1] + bl[n]) * betaf + h1;
            float v2 = (acc[m][n][2] + bl[n]) * betaf + h2;
            float v3 = (acc[m][n][3] + bl[n]) * betaf + h3;
            int rb = m * 16 + 4 * lg;
            int col = col0 + n * 16 + lr;
            sH[(rb + 0) * HID + (col ^ (((rb + 0) & 7) << 3))] = f2bf(v0);
            sH[(rb + 1) * HID + (col ^ (((rb + 1) & 7) << 3))] = f2bf(v1);
            sH[(rb + 2) * HID + (col ^ (((rb + 2) & 7) << 3))] = f2bf(v2);
            sH[(rb + 3) * HID + (col ^ (((rb + 3) & 7) << 3))] = f2bf(v3);
        }
    __syncthreads();

    // ---- P4: out = relu(u @ lin_w1 + lb1) . lin_w2 + lb2 ----
    gemm_phase<8, 256>(sH, sB, WT + OFF_LIN1, nullptr, lr, lg, col0, tid, acc);
#pragma unroll
    for (int n = 0; n < 4; ++n) bl[n] = lin_b1[col0 + n * 16 + lr];
    float w2l[4];
#pragma unroll
    for (int n = 0; n < 4; ++n) w2l[n] = lin_w2[col0 + n * 16 + lr];
#pragma unroll
    for (int m = 0; m < 4; ++m) {
        float p[4] = {0.f, 0.f, 0.f, 0.f};
#pragma unroll
        for (int n = 0; n < 4; ++n)
#pragma unroll
            for (int i = 0; i < 4; ++i)
                p[i] += fmaxf(acc[m][n][i] + bl[n], 0.f) * w2l[n];
#pragma unroll
        for (int i = 0; i < 4; ++i) {
            float s = p[i];
            s += __shfl_xor(s, 1);
            s += __shfl_xor(s, 2);
            s += __shfl_xor(s, 4);
            s += __shfl_xor(s, 8);
            if (lr == 0) sRed[wv * 64 + m * 16 + 4 * lg + i] = s;
        }
    }
    __syncthreads();
    if (tid < 64)
        out[row0 + tid] = sRed[tid] + sRed[64 + tid] + sRed[128 + tid] + sRed[192 + tid] + lin_b2[0];
}

extern "C" void kernel_launch(void* const* d_in, const int* in_sizes, int n_in,
                              void* d_out, int out_size, void* d_ws, size_t ws_size,
                              hipStream_t stream) {
    const float* x      = (const float*)d_in[0];
    const int*   adj    = (const int*)d_in[1];
    const int*   tar    = (const int*)d_in[2];
    const float* beta   = (const float*)d_in[3];
    const float* xcn_w1 = (const float*)d_in[4];
    const float* xcn_b1 = (const float*)d_in[5];
    const float* xcn_w2 = (const float*)d_in[6];
    const float* xcn_b2 = (const float*)d_in[7];
    const float* xcn_w3 = (const float*)d_in[8];
    const float* xcn_b3 = (const float*)d_in[9];
    const float* xij_w1 = (const float*)d_in[10];
    const float* xij_b1 = (const float*)d_in[11];
    const float* xij_w2 = (const float*)d_in[12];
    const float* xij_b2 = (const float*)d_in[13];
    const float* lin_w1 = (const float*)d_in[14];
    const float* lin_b1 = (const float*)d_in[15];
    const float* lin_w2 = (const float*)d_in[16];
    const float* lin_b2 = (const float*)d_in[17];

    unsigned short* WT    = (unsigned short*)d_ws;                     // 576 KiB
    unsigned short* xij_g = (unsigned short*)((char*)d_ws + 589824);   // 4 MiB
    unsigned short* xcn_g = (unsigned short*)((char*)d_ws + 4784128);  // 4 MiB

    edge_prep_k<<<NEDGES / 4, 256, 0, stream>>>(x, adj, tar,
                                                xij_w1, xij_w2, xcn_w1, xcn_w2, xcn_w3, lin_w1,
                                                WT, xij_g, xcn_g);
    mlp_k<<<NEDGES / 64, 256, 0, stream>>>(xij_g, xcn_g, WT,
                                           xij_b1, xij_b2, xcn_b1, xcn_b2, xcn_b3,
                                           lin_b1, lin_w2, lin_b2, beta, (float*)d_out);
}

// Round 9
// 63.817 us; speedup vs baseline: 1.5482x; 1.1983x over previous
//
#include <hip/hip_runtime.h>

// Problem constants (from reference)
#define NNODES 10000
#define DDEG   64
#define NEDGES 32768
#define FIN    64
#define HID    256

typedef __attribute__((ext_vector_type(8))) __bf16 bf16x8;
typedef __attribute__((ext_vector_type(4))) float  f32x4;

__device__ __forceinline__ unsigned short f2bf(float f) {
    unsigned x = __float_as_uint(f);
    return (unsigned short)((x + 0x7FFFu + ((x >> 16) & 1u)) >> 16);  // RNE
}
__device__ __forceinline__ float b2f(unsigned short u) {
    return __uint_as_float(((unsigned)u) << 16);
}

// Blocked transposed-weight layout (bf16): WT[k>>5][n][k&31], tile = 8192 elems (16KB).
#define OFF_XIJ1 0        // K=64  : tiles 0..1
#define OFF_XIJ2 16384    // K=256 : tiles 2..9
#define OFF_XCN1 81920    // tiles 10..11
#define OFF_XCN2 98304    // tiles 12..19
#define OFF_XCN3 163840   // tiles 20..27
#define OFF_LIN1 229376   // tiles 28..35
#define WT_TOTAL 294912
#define NTILES   36

__host__ __device__ constexpr int tile_off(int t) {
    return t < 2  ? OFF_XIJ1 + t * 8192
         : t < 10 ? OFF_XIJ2 + (t - 2) * 8192
         : t < 12 ? OFF_XCN1 + (t - 10) * 8192
         : t < 20 ? OFF_XCN2 + (t - 12) * 8192
         : t < 28 ? OFF_XCN3 + (t - 20) * 8192
         :          OFF_LIN1 + (t - 28) * 8192;
}

// ---- async global->LDS (LDS dest = wave-uniform base + lane*16B) ----
__device__ __forceinline__ void gll16(const unsigned short* g, unsigned short* l) {
    __builtin_amdgcn_global_load_lds(
        (const __attribute__((address_space(1))) unsigned int*)g,
        (__attribute__((address_space(3))) unsigned int*)l, 16, 0, 0);
}
// 16KB tile with 512 threads: 2 gll16/thread (vmcnt cost = 2 per wave)
__device__ __forceinline__ void stage_tile(const unsigned short* g, unsigned short* l,
                                           int tid, int wv) {
#pragma unroll
    for (int c = 0; c < 2; ++c)
        gll16(g + c * 4096 + tid * 8, l + c * 4096 + wv * 512);
}

// Edge stage (1 edge per wave, TLP-hidden) + weight-prep piggyback.
// xij/xcn written PRE-SWIZZLED (elem ^= (row&7)<<3) so linear global_load_lds staging
// lands in the swizzled layout the A-fragment ds_reads expect.
__global__ __launch_bounds__(256) void edge_prep_k(const float* __restrict__ x,
                                                   const int* __restrict__ adj,
                                                   const int* __restrict__ tar,
                                                   const float* __restrict__ xij_w1,
                                                   const float* __restrict__ xij_w2,
                                                   const float* __restrict__ xcn_w1,
                                                   const float* __restrict__ xcn_w2,
                                                   const float* __restrict__ xcn_w3,
                                                   const float* __restrict__ lin_w1,
                                                   unsigned short* __restrict__ WT,
                                                   unsigned short* __restrict__ xij_g,
                                                   unsigned short* __restrict__ xcn_g) {
    const int wv   = threadIdx.x >> 6;
    const int lane = threadIdx.x & 63;
    const int e    = blockIdx.x * 4 + wv;      // grid = NEDGES/4 = 8192

    int i = tar[e];
    int j = tar[NEDGES + e];
    int ni = adj[i * DDEG + lane];
    int nj = adj[j * DDEG + lane];
    float xi = x[i * FIN + lane];
    float xj = x[j * FIN + lane];

    bool found = false;
#pragma unroll
    for (int b = 0; b < 64; ++b)
        found |= (ni == (int)__builtin_amdgcn_readlane(nj, b));
    unsigned long long m = __ballot(found);

    float acc = 0.f;
    while (m) {
        int a = __ffsll(m) - 1;
        m &= m - 1;
        int r = (int)__builtin_amdgcn_readlane(ni, a);
        acc += x[r * FIN + lane];
    }
    int sl = lane ^ ((e & 7) << 3);            // pre-swizzle (row&7 == e&7)
    xij_g[(size_t)e * FIN + sl] = f2bf(xi * xj);
    xcn_g[(size_t)e * FIN + sl] = f2bf(acc);

    // ---- weight-prep piggyback: fp32 W[K,256] -> blocked bf16 WT ----
    if (blockIdx.x < WT_TOTAL / 256) {
        int idx = blockIdx.x * 256 + threadIdx.x;
        const float* src;
        int r;
        if (idx < OFF_XIJ2)      { r = idx - OFF_XIJ1; src = xij_w1; }
        else if (idx < OFF_XCN1) { r = idx - OFF_XIJ2; src = xij_w2; }
        else if (idx < OFF_XCN2) { r = idx - OFF_XCN1; src = xcn_w1; }
        else if (idx < OFF_XCN3) { r = idx - OFF_XCN2; src = xcn_w2; }
        else if (idx < OFF_LIN1) { r = idx - OFF_XCN3; src = xcn_w3; }
        else                     { r = idx - OFF_LIN1; src = lin_w1; }
        int kb  = r >> 13;
        int n   = (r & 8191) >> 5;
        int klo = r & 31;
        WT[idx] = f2bf(src[(kb * 32 + klo) * HID + n]);
    }
}

// One phase of the continuous 36-tile stream, ring-2 buffers, counted vmcnt.
// Per step s (tile t = T0+s):
//   s_waitcnt vmcnt(2) lgkmcnt(0)   // t landed (only t+1's 2 loads outstanding);
//                                   // lgkm0 covers prior epilogue ds_writes
//   s_barrier                       // raw: loads stay in flight across it
//   ds_read A(2) + B(4); 8 x MFMA (setprio 1)
//   s_waitcnt lgkmcnt(0); s_barrier // all waves done reading ring[t&1]
//   stage tile t+2 into ring[t&1]   // 2 loads; in flight for a full next step
// acc[2][4]: wave quadrant rows r0..r0+32, cols col0..col0+64.
template <int T0, int NT, int LDA>
__device__ __forceinline__ void run_phase(const unsigned short* As,
                                          unsigned short* ring,
                                          const unsigned short* __restrict__ WT,
                                          int lr, int lg, int col0, int r0,
                                          int tid, int wv, f32x4 acc[2][4]) {
#pragma unroll
    for (int m = 0; m < 2; ++m)
#pragma unroll
        for (int n = 0; n < 4; ++n) acc[m][n] = (f32x4){0.f, 0.f, 0.f, 0.f};
    const int sw = (lr & 7) << 3;
#pragma unroll
    for (int s = 0; s < NT; ++s) {
        if (T0 + s + 1 < NTILES)
            asm volatile("s_waitcnt vmcnt(2) lgkmcnt(0)" ::: "memory");
        else
            asm volatile("s_waitcnt vmcnt(0) lgkmcnt(0)" ::: "memory");
        __builtin_amdgcn_s_barrier();
        const unsigned short* cur = ring + ((T0 + s) & 1) * 8192;
        bf16x8 a[2], b[4];
#pragma unroll
        for (int n = 0; n < 4; ++n)
            b[n] = *reinterpret_cast<const bf16x8*>(&cur[(col0 + n * 16 + lr) * 32 + 8 * lg]);
#pragma unroll
        for (int m = 0; m < 2; ++m)
            a[m] = *reinterpret_cast<const bf16x8*>(
                &As[(r0 + m * 16 + lr) * LDA + ((s * 32 + 8 * lg) ^ sw)]);
        __builtin_amdgcn_s_setprio(1);
#pragma unroll
        for (int m = 0; m < 2; ++m)
#pragma unroll
            for (int n = 0; n < 4; ++n)
                acc[m][n] = __builtin_amdgcn_mfma_f32_16x16x32_bf16(a[m], b[n], acc[m][n], 0, 0, 0);
        __builtin_amdgcn_s_setprio(0);
        asm volatile("s_waitcnt lgkmcnt(0)" ::: "memory");
        __builtin_amdgcn_s_barrier();
        if (T0 + s + 2 < NTILES)
            stage_tile(WT + tile_off(T0 + s + 2), ring + ((T0 + s) & 1) * 8192, tid, wv);
    }
}

// Fused MLP over 64-edge tiles; 8 waves (512 thr); wave wv: rows r0=(wv>>2)*32..+32,
// cols col0=(wv&3)*64..+64. D-frag lane l: row=r0+m*16+4*(l>>4)+i, col=col0+n*16+(l&15).
// LDS exactly 80KB -> 2 blocks/CU (16 waves/CU = 4 waves/SIMD).
__global__ __launch_bounds__(512, 4) void mlp_k(const unsigned short* __restrict__ xij_g,
                                                const unsigned short* __restrict__ xcn_g,
                                                const unsigned short* __restrict__ WT,
                                                const float* __restrict__ xij_b1,
                                                const float* __restrict__ xij_b2,
                                                const float* __restrict__ xcn_b1,
                                                const float* __restrict__ xcn_b2,
                                                const float* __restrict__ xcn_b3,
                                                const float* __restrict__ lin_b1,
                                                const float* __restrict__ lin_w2,
                                                const float* __restrict__ lin_b2,
                                                const float* __restrict__ beta,
                                                float* __restrict__ out) {
    __shared__ unsigned short sXij[64 * 64];   // 8 KB (later aliased as f32 sRed)
    __shared__ unsigned short sXcn[64 * 64];   // 8 KB
    __shared__ unsigned short sH[64 * 256];    // 32 KB activation (in-place reuse)
    __shared__ unsigned short sB[2 * 8192];    // 32 KB weight ring

    const int tid  = threadIdx.x;
    const int wv   = tid >> 6;
    const int lane = tid & 63;
    const int lr   = lane & 15;
    const int lg   = lane >> 4;
    const int r0   = (wv >> 2) * 32;
    const int col0 = (wv & 3) * 64;
    const int row0 = blockIdx.x * 64;

    // prologue staging: sXij(1) + sXcn(1) + t0(2) + t1(2) = 6 outstanding/wave.
    // step0's vmcnt(2) leaves t1's 2 -> sXij,sXcn,t0 complete (FIFO).
    gll16(xij_g + (size_t)row0 * FIN + tid * 8, sXij + wv * 512);
    gll16(xcn_g + (size_t)row0 * FIN + tid * 8, sXcn + wv * 512);
    stage_tile(WT + tile_off(0), sB, tid, wv);
    stage_tile(WT + tile_off(1), sB + 8192, tid, wv);
    const float betaf = beta[0];

    f32x4 acc[2][4];
    float bl[4];

    // ---- P1: h1 = relu(xij @ xij_w1 + b1) -> sH ----
    run_phase<0, 2, 64>(sXij, sB, WT, lr, lg, col0, r0, tid, wv, acc);
#pragma unroll
    for (int n = 0; n < 4; ++n) bl[n] = xij_b1[col0 + n * 16 + lr];
#pragma unroll
    for (int m = 0; m < 2; ++m)
#pragma unroll
        for (int n = 0; n < 4; ++n)
#pragma unroll
            for (int i = 0; i < 4; ++i) {
                int row = r0 + m * 16 + 4 * lg + i;
                int col = col0 + n * 16 + lr;
                sH[row * HID + (col ^ ((row & 7) << 3))] = f2bf(fmaxf(acc[m][n][i] + bl[n], 0.f));
            }

    // ---- P2: h_ij = h1 @ xij_w2 + b2 -> registers (packed bf16, 16 VGPR) ----
    run_phase<2, 8, 256>(sH, sB, WT, lr, lg, col0, r0, tid, wv, acc);
#pragma unroll
    for (int n = 0; n < 4; ++n) bl[n] = xij_b2[col0 + n * 16 + lr];
    unsigned hij_lo[2][4], hij_hi[2][4];
#pragma unroll
    for (int m = 0; m < 2; ++m)
#pragma unroll
        for (int n = 0; n < 4; ++n) {
            hij_lo[m][n] = ((unsigned)f2bf(acc[m][n][1] + bl[n]) << 16) | f2bf(acc[m][n][0] + bl[n]);
            hij_hi[m][n] = ((unsigned)f2bf(acc[m][n][3] + bl[n]) << 16) | f2bf(acc[m][n][2] + bl[n]);
        }

    // ---- P3: t1 = relu(xcn @ xcn_w1 + b1) -> sH (P2 readers synced at its last barrier) ----
    run_phase<10, 2, 64>(sXcn, sB, WT, lr, lg, col0, r0, tid, wv, acc);
#pragma unroll
    for (int n = 0; n < 4; ++n) bl[n] = xcn_b1[col0 + n * 16 + lr];
#pragma unroll
    for (int m = 0; m < 2; ++m)
#pragma unroll
        for (int n = 0; n < 4; ++n)
#pragma unroll
            for (int i = 0; i < 4; ++i) {
                int row = r0 + m * 16 + 4 * lg + i;
                int col = col0 + n * 16 + lr;
                sH[row * HID + (col ^ ((row & 7) << 3))] = f2bf(fmaxf(acc[m][n][i] + bl[n], 0.f));
            }

    // ---- P4: t2 = relu(t1 @ xcn_w2 + b2) -> sH in place ----
    run_phase<12, 8, 256>(sH, sB, WT, lr, lg, col0, r0, tid, wv, acc);
#pragma unroll
    for (int n = 0; n < 4; ++n) bl[n] = xcn_b2[col0 + n * 16 + lr];
#pragma unroll
    for (int m = 0; m < 2; ++m)
#pragma unroll
        for (int n = 0; n < 4; ++n)
#pragma unroll
            for (int i = 0; i < 4; ++i) {
                int row = r0 + m * 16 + 4 * lg + i;
                int col = col0 + n * 16 + lr;
                sH[row * HID + (col ^ ((row & 7) << 3))] = f2bf(fmaxf(acc[m][n][i] + bl[n], 0.f));
            }

    // ---- P5: u = (t2 @ xcn_w3 + b3) * beta + h_ij -> sH in place ----
    run_phase<20, 8, 256>(sH, sB, WT, lr, lg, col0, r0, tid, wv, acc);
#pragma unroll
    for (int n = 0; n < 4; ++n) bl[n] = xcn_b3[col0 + n * 16 + lr];
#pragma unroll
    for (int m = 0; m < 2; ++m)
#pragma unroll
        for (int n = 0; n < 4; ++n) {
            float h0 = b2f((unsigned short)(hij_lo[m][n] & 0xFFFF));
            float h1 = b2f((unsigned short)(hij_lo[m][n] >> 16));
            float h2 = b2f((unsigned short)(hij_hi[m][n] & 0xFFFF));
            float h3 = b2f((unsigned short)(hij_hi[m][n] >> 16));
            float v0 = (acc[m][n][0] + bl[n]) * betaf + h0;
            float v1 = (acc[m][n][1] + bl[n]) * betaf + h1;
            float v2 = (acc[m][n][2] + bl[n]) * betaf + h2;
            float v3 = (acc[m][n][3] + bl[n]) * betaf + h3;
            int rb = r0 + m * 16 + 4 * lg;
            int col = col0 + n * 16 + lr;
            sH[(rb + 0) * HID + (col ^ (((rb + 0) & 7) << 3))] = f2bf(v0);
            sH[(rb + 1) * HID + (col ^ (((rb + 1) & 7) << 3))] = f2bf(v1);
            sH[(rb + 2) * HID + (col ^ (((rb + 2) & 7) << 3))] = f2bf(v2);
            sH[(rb + 3) * HID + (col ^ (((rb + 3) & 7) << 3))] = f2bf(v3);
        }

    // ---- P6: out = relu(u @ lin_w1 + lb1) . lin_w2 + lb2 ----
    run_phase<28, 8, 256>(sH, sB, WT, lr, lg, col0, r0, tid, wv, acc);
#pragma unroll
    for (int n = 0; n < 4; ++n) bl[n] = lin_b1[col0 + n * 16 + lr];
    float w2l[4];
#pragma unroll
    for (int n = 0; n < 4; ++n) w2l[n] = lin_w2[col0 + n * 16 + lr];
    float* sRed = (float*)sXij;   // sXij dead since P1; 4*64 floats
#pragma unroll
    for (int m = 0; m < 2; ++m) {
        float p[4] = {0.f, 0.f, 0.f, 0.f};
#pragma unroll
        for (int n = 0; n < 4; ++n)
#pragma unroll
            for (int i = 0; i < 4; ++i)
                p[i] += fmaxf(acc[m][n][i] + bl[n], 0.f) * w2l[n];
#pragma unroll
        for (int i = 0; i < 4; ++i) {
            float s = p[i];
            s += __shfl_xor(s, 1);
            s += __shfl_xor(s, 2);
            s += __shfl_xor(s, 4);
            s += __shfl_xor(s, 8);
            if (lr == 0) sRed[(wv & 3) * 64 + r0 + m * 16 + 4 * lg + i] = s;
        }
    }
    __syncthreads();   // stream drained (P6 last step waited vmcnt(0)); plain barrier OK
    if (tid < 64)
        out[row0 + tid] = sRed[tid] + sRed[64 + tid] + sRed[128 + tid] + sRed[192 + tid] + lin_b2[0];
}

extern "C" void kernel_launch(void* const* d_in, const int* in_sizes, int n_in,
                              void* d_out, int out_size, void* d_ws, size_t ws_size,
                              hipStream_t stream) {
    const float* x      = (const float*)d_in[0];
    const int*   adj    = (const int*)d_in[1];
    const int*   tar    = (const int*)d_in[2];
    const float* beta   = (const float*)d_in[3];
    const float* xcn_w1 = (const float*)d_in[4];
    const float* xcn_b1 = (const float*)d_in[5];
    const float* xcn_w2 = (const float*)d_in[6];
    const float* xcn_b2 = (const float*)d_in[7];
    const float* xcn_w3 = (const float*)d_in[8];
    const float* xcn_b3 = (const float*)d_in[9];
    const float* xij_w1 = (const float*)d_in[10];
    const float* xij_b1 = (const float*)d_in[11];
    const float* xij_w2 = (const float*)d_in[12];
    const float* xij_b2 = (const float*)d_in[13];
    const float* lin_w1 = (const float*)d_in[14];
    const float* lin_b1 = (const float*)d_in[15];
    const float* lin_w2 = (const float*)d_in[16];
    const float* lin_b2 = (const float*)d_in[17];

    unsigned short* WT    = (unsigned short*)d_ws;                     // 576 KiB
    unsigned short* xij_g = (unsigned short*)((char*)d_ws + 589824);   // 4 MiB
    unsigned short* xcn_g = (unsigned short*)((char*)d_ws + 4784128);  // 4 MiB

    edge_prep_k<<<NEDGES / 4, 256, 0, stream>>>(x, adj, tar,
                                                xij_w1, xij_w2, xcn_w1, xcn_w2, xcn_w3, lin_w1,
                                                WT, xij_g, xcn_g);
    mlp_k<<<NEDGES / 64, 512, 0, stream>>>(xij_g, xcn_g, WT,
                                           xij_b1, xij_b2, xcn_b1, xcn_b2, xcn_b3,
                                           lin_b1, lin_w2, lin_b2, beta, (float*)d_out);
}